// Round 1
// baseline (227.201 us; speedup 1.0000x reference)
//
#include <hip/hip_runtime.h>
#include <math.h>

// Problem constants (fixed by setup_inputs)
#define BATCH 4
#define NHEAD 8
#define HD 24          // head dim (channels per head)
#define CH 192         // total channels
#define HW 16384       // h*w
#define NSPLIT 64      // hw splits for pass 1
#define CHUNK 256      // HW / NSPLIT
#define LDS_STRIDE 264 // 256 + 8 pad: 16B-aligned rows, 2-way-max bank aliasing

// ws layout (floats):
//   sqq_part: [768][64]          off 0
//   sqk_part: [768][64]          off 49152
//   S_part:   [32][576][64]      off 98304
//   Mt:       [4][192][192]      off 1277952   (c-major: [b][c][o])
// total 1425408 floats = 5.7 MB
#define OFF_SQK 49152
#define OFF_S   98304
#define OFF_M   1277952

// ---------------------------------------------------------------------------
// Kernel A: per (b,head, hw-split): raw sumsq of q,k rows + raw 24x24 Gram
// partial dot products. grid (32, 64), block 256.
// ---------------------------------------------------------------------------
__global__ __launch_bounds__(256) void kA(const float* __restrict__ q,
                                          const float* __restrict__ k,
                                          float* __restrict__ ws) {
    __shared__ float qs[HD * LDS_STRIDE];
    __shared__ float ks[HD * LDS_STRIDE];

    const int bh   = blockIdx.x;   // 0..31
    const int sp   = blockIdx.y;   // 0..63
    const int t    = threadIdx.x;
    const int lane = t & 63;
    const int wave = t >> 6;       // 0..3

    const float* qb = q + (size_t)bh * HD * HW + sp * CHUNK;
    const float* kb = k + (size_t)bh * HD * HW + sp * CHUNK;
    float* sqq = ws;
    float* sqk = ws + OFF_SQK;
    float* Sp  = ws + OFF_S;

    // ---- stage to LDS + per-row sumsq (each (iter,wave) owns one row) ----
    #pragma unroll
    for (int it = 0; it < 6; ++it) {
        const int row = it * 4 + wave;      // covers 0..23 exactly once
        const int col = lane * 4;
        float4 qv = *(const float4*)(qb + (size_t)row * HW + col);
        float4 kv = *(const float4*)(kb + (size_t)row * HW + col);
        *(float4*)&qs[row * LDS_STRIDE + col] = qv;
        *(float4*)&ks[row * LDS_STRIDE + col] = kv;
        float sq = qv.x*qv.x + qv.y*qv.y + qv.z*qv.z + qv.w*qv.w;
        float sk = kv.x*kv.x + kv.y*kv.y + kv.z*kv.z + kv.w*kv.w;
        #pragma unroll
        for (int off = 32; off > 0; off >>= 1) {
            sq += __shfl_down(sq, off, 64);
            sk += __shfl_down(sk, off, 64);
        }
        if (lane == 0) {
            sqq[(bh * HD + row) * NSPLIT + sp] = sq;
            sqk[(bh * HD + row) * NSPLIT + sp] = sk;
        }
    }
    __syncthreads();

    // ---- 24x24 Gram partials: 3x3 micro-tile, 8x8 lane grid, wave = n-group
    const int i0 = (lane >> 3) * 3;
    const int j0 = (lane & 7) * 3;
    const int n0 = wave * 64;

    float4 acc[3][3];
    #pragma unroll
    for (int a = 0; a < 3; ++a)
        #pragma unroll
        for (int bb = 0; bb < 3; ++bb) acc[a][bb] = make_float4(0.f, 0.f, 0.f, 0.f);

    for (int n = n0; n < n0 + 64; n += 4) {
        float4 qa[3], kv[3];
        #pragma unroll
        for (int a = 0; a < 3; ++a) qa[a] = *(float4*)&qs[(i0 + a) * LDS_STRIDE + n];
        #pragma unroll
        for (int bb = 0; bb < 3; ++bb) kv[bb] = *(float4*)&ks[(j0 + bb) * LDS_STRIDE + n];
        #pragma unroll
        for (int a = 0; a < 3; ++a)
            #pragma unroll
            for (int bb = 0; bb < 3; ++bb) {
                acc[a][bb].x = fmaf(qa[a].x, kv[bb].x, acc[a][bb].x);
                acc[a][bb].y = fmaf(qa[a].y, kv[bb].y, acc[a][bb].y);
                acc[a][bb].z = fmaf(qa[a].z, kv[bb].z, acc[a][bb].z);
                acc[a][bb].w = fmaf(qa[a].w, kv[bb].w, acc[a][bb].w);
            }
    }

    __syncthreads();                 // all LDS reads done; reuse qs as reducer
    float* red = qs;                 // [576][4]
    #pragma unroll
    for (int a = 0; a < 3; ++a)
        #pragma unroll
        for (int bb = 0; bb < 3; ++bb) {
            float s = acc[a][bb].x + acc[a][bb].y + acc[a][bb].z + acc[a][bb].w;
            red[((i0 + a) * HD + (j0 + bb)) * 4 + wave] = s;
        }
    __syncthreads();
    for (int e = t; e < HD * HD; e += 256) {
        float v = red[e * 4] + red[e * 4 + 1] + red[e * 4 + 2] + red[e * 4 + 3];
        Sp[((size_t)bh * (HD * HD) + e) * NSPLIT + sp] = v;
    }
}

// ---------------------------------------------------------------------------
// Kernel B: per (b,head): finalize norms, logits, softmax, and fold
// proj_w * attn * diag(kinv) into M' [b][c][o]. grid 32, block 256.
// ---------------------------------------------------------------------------
__global__ __launch_bounds__(256) void kB(const float* __restrict__ scale,
                                          const float* __restrict__ w,
                                          float* __restrict__ ws) {
    const int bh = blockIdx.x;
    const int b  = bh >> 3;
    const int h  = bh & 7;
    const int t  = threadIdx.x;

    __shared__ float qinv[HD], kinv[HD];
    __shared__ float A[HD * HD];
    __shared__ float wl[CH * HD];   // proj_w[:, h*24 .. h*24+23]

    const float* sqq = ws;
    const float* sqk = ws + OFF_SQK;
    const float* Sp  = ws + OFF_S;
    float* Mt = ws + OFF_M;

    if (t < 48) {
        const float* src = (t < HD) ? (sqq + (bh * HD + t) * NSPLIT)
                                    : (sqk + (bh * HD + (t - HD)) * NSPLIT);
        float s = 0.f;
        for (int i = 0; i < NSPLIT; ++i) s += src[i];
        float inv = 1.0f / fmaxf(sqrtf(s), 1e-12f);
        if (t < HD) qinv[t] = inv; else kinv[t - HD] = inv;
    }
    for (int idx = t; idx < CH * HD; idx += 256) {
        int o = idx / HD, dd = idx % HD;
        wl[idx] = w[o * CH + h * HD + dd];
    }
    __syncthreads();

    const float sc = scale[h];
    for (int e = t; e < HD * HD; e += 256) {
        const float* sp = Sp + ((size_t)bh * (HD * HD) + e) * NSPLIT;
        float s = 0.f;
        for (int i = 0; i < NSPLIT; ++i) s += sp[i];
        A[e] = s * qinv[e / HD] * kinv[e % HD] * sc;
    }
    __syncthreads();

    if (t < HD) {   // softmax along j for row t
        float m = -1e30f;
        for (int j = 0; j < HD; ++j) m = fmaxf(m, A[t * HD + j]);
        float sum = 0.f;
        for (int j = 0; j < HD; ++j) {
            float v = expf(A[t * HD + j] - m);
            A[t * HD + j] = v;
            sum += v;
        }
        float r = 1.0f / sum;
        for (int j = 0; j < HD; ++j) A[t * HD + j] *= r;
    }
    __syncthreads();

    // M'[b][h*24+j][o] = (sum_i w[o, h*24+i] * A[i][j]) * kinv[j]
    for (int idx = t; idx < CH * HD; idx += 256) {
        int o = idx / HD, j = idx % HD;
        float v = 0.f;
        #pragma unroll
        for (int i = 0; i < HD; ++i) v = fmaf(wl[o * HD + i], A[i * HD + j], v);
        Mt[(size_t)b * CH * CH + (h * HD + j) * CH + o] = v * kinv[j];
    }
}

// ---------------------------------------------------------------------------
// Kernel C: out[b][o][n] = sum_c M'[b][c][o] * k[b][c][n]
// Tile 64 o x 256 n, micro 8x8 per thread, c-chunks of 8.
// grid (64, 3, 4), block 256.
// ---------------------------------------------------------------------------
#define OTILE 64
#define NTILE 256
#define CCH   8

__device__ __forceinline__ void fma4(float4& a, float s, const float4& v) {
    a.x = fmaf(s, v.x, a.x); a.y = fmaf(s, v.y, a.y);
    a.z = fmaf(s, v.z, a.z); a.w = fmaf(s, v.w, a.w);
}

__global__ __launch_bounds__(256) void kC(const float* __restrict__ k,
                                          const float* __restrict__ ws,
                                          float* __restrict__ out) {
    __shared__ float Mall[CH * OTILE];   // [c][o]  48 KB
    __shared__ float kt[CCH * NTILE];    // 8 KB

    const int t  = threadIdx.x;
    const int nb = blockIdx.x * NTILE;
    const int ob = blockIdx.y * OTILE;
    const int b  = blockIdx.z;

    const float* Mt = ws + OFF_M + (size_t)b * CH * CH;
    const float* kb = k + (size_t)b * CH * HW;
    float* op = out + (size_t)b * CH * HW;

    for (int idx = t; idx < CH * OTILE; idx += 256) {
        int c = idx >> 6, o = idx & 63;
        Mall[idx] = Mt[c * CH + ob + o];
    }

    const int po = t >> 5;   // 0..7 -> o in {po*4..+3, 32+po*4..+3}
    const int pn = t & 31;   // 0..31 -> n in {pn*4..+3, 128+pn*4..+3}

    float4 acc[8][2];
    #pragma unroll
    for (int a = 0; a < 8; ++a) { acc[a][0] = make_float4(0,0,0,0); acc[a][1] = make_float4(0,0,0,0); }

    for (int c0 = 0; c0 < CH; c0 += CCH) {
        __syncthreads();   // also covers Mall staging on first pass
        #pragma unroll
        for (int it = 0; it < 2; ++it) {
            int idx = it * 256 + t;             // 512 float4 loads = 2048 floats
            int cc = idx >> 6, col = (idx & 63) * 4;
            *(float4*)&kt[cc * NTILE + col] =
                *(const float4*)(kb + (size_t)(c0 + cc) * HW + nb + col);
        }
        __syncthreads();
        #pragma unroll
        for (int cc = 0; cc < CCH; ++cc) {
            float4 m0 = *(float4*)&Mall[(c0 + cc) * OTILE + po * 4];
            float4 m1 = *(float4*)&Mall[(c0 + cc) * OTILE + 32 + po * 4];
            float4 k0 = *(float4*)&kt[cc * NTILE + pn * 4];
            float4 k1 = *(float4*)&kt[cc * NTILE + 128 + pn * 4];
            fma4(acc[0][0], m0.x, k0); fma4(acc[0][1], m0.x, k1);
            fma4(acc[1][0], m0.y, k0); fma4(acc[1][1], m0.y, k1);
            fma4(acc[2][0], m0.z, k0); fma4(acc[2][1], m0.z, k1);
            fma4(acc[3][0], m0.w, k0); fma4(acc[3][1], m0.w, k1);
            fma4(acc[4][0], m1.x, k0); fma4(acc[4][1], m1.x, k1);
            fma4(acc[5][0], m1.y, k0); fma4(acc[5][1], m1.y, k1);
            fma4(acc[6][0], m1.z, k0); fma4(acc[6][1], m1.z, k1);
            fma4(acc[7][0], m1.w, k0); fma4(acc[7][1], m1.w, k1);
        }
    }

    #pragma unroll
    for (int a = 0; a < 8; ++a) {
        int o = ob + ((a < 4) ? (po * 4 + a) : (32 + po * 4 + (a - 4)));
        *(float4*)(op + (size_t)o * HW + nb + pn * 4)       = acc[a][0];
        *(float4*)(op + (size_t)o * HW + nb + 128 + pn * 4) = acc[a][1];
    }
}

extern "C" void kernel_launch(void* const* d_in, const int* in_sizes, int n_in,
                              void* d_out, int out_size, void* d_ws, size_t ws_size,
                              hipStream_t stream) {
    const float* in1   = (const float*)d_in[0];
    const float* in2   = (const float*)d_in[1];
    const float* scale = (const float*)d_in[2];
    const float* projw = (const float*)d_in[3];
    float* ws  = (float*)d_ws;   // needs 5.7 MB
    float* out = (float*)d_out;

    kA<<<dim3(32, NSPLIT), 256, 0, stream>>>(in1, in2, ws);
    kB<<<32, 256, 0, stream>>>(scale, projw, ws);
    kC<<<dim3(HW / NTILE, CH / OTILE, BATCH), 256, 0, stream>>>(in2, ws, out);
}